// Round 3
// baseline (206.385 us; speedup 1.0000x reference)
//
#include <hip/hip_runtime.h>
#include <hip/hip_bf16.h>

#define BATCH 4096
#define LQ 30
#define LD 128
#define EMB 50
#define KPAD 72        // bf16 elems per row; 64 used, stride 144B = 36 dwords (2-way bank alias, free)
#define ROWS 160       // rows 0..31 = queries (30 real), 32..159 = docs
#define KN 21
#define THREADS 512
#define EM1 0.36787944117144233f

typedef __attribute__((ext_vector_type(8))) short short8;
typedef __attribute__((ext_vector_type(4))) float f32x4;

__device__ __forceinline__ float grp16_sum(float v) {
  v += __shfl_xor(v, 8);
  v += __shfl_xor(v, 4);
  v += __shfl_xor(v, 2);
  v += __shfl_xor(v, 1);
  return v;
}

__global__ __launch_bounds__(THREADS, 4) void knrm_pair_kernel(
    const int* __restrict__ q1, const int* __restrict__ d1,
    const int* __restrict__ q2, const int* __restrict__ d2,
    const float* __restrict__ emb, const float* __restrict__ mlp_w,
    const float* __restrict__ mlp_b, float* __restrict__ logits)
{
  __shared__ __hip_bfloat16 shi[ROWS][KPAD];
  __shared__ __hip_bfloat16 slo[ROWS][KPAD];
  __shared__ int toks[ROWS];
  __shared__ float kacc2[2][4][16][KN];   // [qtile][dpair][qcol][kernel]

  const int b = blockIdx.x;
  const int pair = blockIdx.y;
  const int tid = threadIdx.x;
  const int* __restrict__ qp = pair ? q2 : q1;
  const int* __restrict__ dp = pair ? d2 : d1;

  // ---- token ids: rows 0..29 query, 30..31 pad, 32..159 doc ----
  if (tid < ROWS) {
    int t = -1;
    if (tid < LQ) t = qp[b * LQ + tid];
    else if (tid >= 32) t = dp[b * LD + (tid - 32)];
    toks[tid] = t;
  }
  __syncthreads();

  // ---- gather + L2-normalize + hi/lo bf16 split into LDS ----
  {
    const int lg = tid & 15;
    const int g = tid >> 4;            // 32 groups, one row each per iter
    #pragma unroll
    for (int it = 0; it < 5; ++it) {
      const int row = it * 32 + g;
      const int tok = toks[row];
      float4 v4 = make_float4(0.f, 0.f, 0.f, 0.f);
      if (tok >= 0) {
        if (lg < 12) {
          v4 = *(const float4*)(emb + (long)tok * EMB + 4 * lg);
        } else if (lg == 12) {          // elems 48,49 only (avoid OOB past row)
          float2 t2 = *(const float2*)(emb + (long)tok * EMB + 48);
          v4.x = t2.x; v4.y = t2.y;
        }
      }
      float ss = v4.x*v4.x + v4.y*v4.y + v4.z*v4.z + v4.w*v4.w;
      ss = grp16_sum(ss);
      const float scale = 1.0f / fmaxf(sqrtf(ss), 1e-12f);
      ushort4 hs, ls;
      const float e0 = v4.x * scale, e1 = v4.y * scale,
                  e2 = v4.z * scale, e3 = v4.w * scale;
      __hip_bfloat16 h;
      h = __float2bfloat16(e0); hs.x = __hip_bfloat16_raw(h).x;
      ls.x = __hip_bfloat16_raw(__float2bfloat16(e0 - __bfloat162float(h))).x;
      h = __float2bfloat16(e1); hs.y = __hip_bfloat16_raw(h).x;
      ls.y = __hip_bfloat16_raw(__float2bfloat16(e1 - __bfloat162float(h))).x;
      h = __float2bfloat16(e2); hs.z = __hip_bfloat16_raw(h).x;
      ls.z = __hip_bfloat16_raw(__float2bfloat16(e2 - __bfloat162float(h))).x;
      h = __float2bfloat16(e3); hs.w = __hip_bfloat16_raw(h).x;
      ls.w = __hip_bfloat16_raw(__float2bfloat16(e3 - __bfloat162float(h))).x;
      *(ushort4*)&shi[row][4 * lg] = hs;
      *(ushort4*)&slo[row][4 * lg] = ls;
    }
  }
  __syncthreads();

  // ---- phase 2: wave w = (qtile, dpair); 2 doc-tiles per wave ----
  const int lane = tid & 63;
  const int w = tid >> 6;             // 0..7
  const int qtile = w >> 2;           // 0..1
  const int dpair = w & 3;            // 0..3  -> dtiles {dpair, dpair+4}
  const int col = lane & 15;          // C col = query within tile
  const int kgrp = lane >> 4;         // 0..3
  const int klane = kgrp * 8;

  const int qrow = qtile * 16 + col;
  const short8 Bh0 = *(const short8*)&shi[qrow][klane];
  const short8 Bh1 = *(const short8*)&shi[qrow][32 + klane];
  const short8 Bl0 = *(const short8*)&slo[qrow][klane];
  const short8 Bl1 = *(const short8*)&slo[qrow][32 + klane];
  const int qtok = toks[qrow];

  float racc[KN];
  #pragma unroll
  for (int k = 0; k < KN; ++k) racc[k] = 0.0f;
  float cnt = 0.0f;

  #pragma unroll 1
  for (int s = 0; s < 2; ++s) {
    const int dtile = dpair + s * 4;
    const int arow = 32 + dtile * 16 + col;      // A row = doc
    const short8 Ah0 = *(const short8*)&shi[arow][klane];
    const short8 Ah1 = *(const short8*)&shi[arow][32 + klane];
    const short8 Al0 = *(const short8*)&slo[arow][klane];
    const short8 Al1 = *(const short8*)&slo[arow][32 + klane];

    f32x4 acc = {0.0f, 0.0f, 0.0f, 0.0f};
    acc = __builtin_amdgcn_mfma_f32_16x16x32_bf16(Ah0, Bh0, acc, 0, 0, 0);
    acc = __builtin_amdgcn_mfma_f32_16x16x32_bf16(Ah1, Bh1, acc, 0, 0, 0);
    acc = __builtin_amdgcn_mfma_f32_16x16x32_bf16(Al0, Bh0, acc, 0, 0, 0);
    acc = __builtin_amdgcn_mfma_f32_16x16x32_bf16(Al1, Bh1, acc, 0, 0, 0);
    acc = __builtin_amdgcn_mfma_f32_16x16x32_bf16(Ah0, Bl0, acc, 0, 0, 0);
    acc = __builtin_amdgcn_mfma_f32_16x16x32_bf16(Ah1, Bl1, acc, 0, 0, 0);

    const int dbase = 32 + dtile * 16 + kgrp * 4; // C row = doc
    #pragma unroll
    for (int r = 0; r < 4; ++r) {
      const float x = acc[r];
      cnt += (toks[dbase + r] == qtok) ? 1.0f : 0.0f;  // exact-match kernel
      const float t = x - 0.05f;
      const float v = __expf(-50.0f * t * t);
      const float E = __expf(10.0f * x);
      const float F = __expf(-10.0f * x);
      racc[10] += v;
      float vu = v, ru = E * EM1;
      #pragma unroll
      for (int k = 11; k <= 19; ++k) { vu *= ru; racc[k] += vu; ru *= EM1; }
      float vd = v, rd = F;
      #pragma unroll
      for (int k = 9; k >= 0; --k) { vd *= rd; racc[k] += vd; rd *= EM1; }
    }
  }
  racc[20] = cnt;

  // reduce over the 4 kgrp row-groups (docs) within the wave
  #pragma unroll
  for (int k = 0; k < KN; ++k) {
    racc[k] += __shfl_xor(racc[k], 16);
    racc[k] += __shfl_xor(racc[k], 32);
  }

  if (lane < 16) {
    #pragma unroll
    for (int k = 0; k < KN; ++k) kacc2[qtile][dpair][lane][k] = racc[k];
  }
  __syncthreads();

  // ---- final: wave 0 combines 4 doc-slices, applies log1p + MLP ----
  if (tid < 64) {
    float s = 0.0f;
    if (tid < 32) {
      const int qt = tid >> 4, q = tid & 15;
      if (qt * 16 + q < LQ) {
        #pragma unroll
        for (int k = 0; k < KN; ++k) {
          const float S = kacc2[qt][0][q][k] + kacc2[qt][1][q][k] +
                          kacc2[qt][2][q][k] + kacc2[qt][3][q][k];
          s = fmaf(mlp_w[k], __logf(1.0f + S), s);
        }
      }
    }
    s += __shfl_xor(s, 1);
    s += __shfl_xor(s, 2);
    s += __shfl_xor(s, 4);
    s += __shfl_xor(s, 8);
    s += __shfl_xor(s, 16);
    s += __shfl_xor(s, 32);
    if (tid == 0) logits[pair * BATCH + b] = s + mlp_b[0];
  }
}

__global__ void knrm_combine_kernel(const float* __restrict__ logits,
                                    float* __restrict__ out) {
  int i = blockIdx.x * 256 + threadIdx.x;
  if (i < BATCH) {
    float z = logits[i] - logits[BATCH + i];
    out[i] = 1.0f / (1.0f + __expf(-z));
  }
}

extern "C" void kernel_launch(void* const* d_in, const int* in_sizes, int n_in,
                              void* d_out, int out_size, void* d_ws, size_t ws_size,
                              hipStream_t stream) {
  const int* q1 = (const int*)d_in[0];
  const int* d1 = (const int*)d_in[1];
  const int* q2 = (const int*)d_in[2];
  const int* d2 = (const int*)d_in[3];
  const float* emb = (const float*)d_in[4];
  const float* mlp_w = (const float*)d_in[5];
  const float* mlp_b = (const float*)d_in[6];
  float* out = (float*)d_out;
  float* logits = (float*)d_ws;   // 2*BATCH floats of scratch

  dim3 grid(BATCH, 2);
  knrm_pair_kernel<<<grid, THREADS, 0, stream>>>(q1, d1, q2, d2, emb, mlp_w, mlp_b, logits);
  knrm_combine_kernel<<<(BATCH + 255) / 256, 256, 0, stream>>>(logits, out);
}

// Round 5
// 186.906 us; speedup vs baseline: 1.1042x; 1.1042x over previous
//
#include <hip/hip_runtime.h>
#include <hip/hip_bf16.h>

#define BATCH 4096
#define LQ 30
#define LD 128
#define EMB 50
#define KPAD 72        // bf16 elems per row; stride 144B (2-way bank alias on frag reads = free)
#define ROWS 160       // rows 0..31 = queries (30 real), 32..159 = docs
#define KN 21
#define THREADS 512
#define EM1 0.36787944117144233f     // e^-1 (chain ratio decay)
#define K10 14.426950408889634f      // 10/ln2
#define C50 72.134752044448169f      // 50/ln2

typedef __attribute__((ext_vector_type(8))) short short8;
typedef __attribute__((ext_vector_type(4))) float f32x4;
typedef __attribute__((ext_vector_type(2))) float f32x2;

#define EXP2(x) __builtin_amdgcn_exp2f(x)

__device__ __forceinline__ float grp16_sum(float v) {
  v += __shfl_xor(v, 8);
  v += __shfl_xor(v, 4);
  v += __shfl_xor(v, 2);
  v += __shfl_xor(v, 1);
  return v;
}

__global__ __launch_bounds__(THREADS, 4) void knrm_pair_kernel(
    const int* __restrict__ q1, const int* __restrict__ d1,
    const int* __restrict__ q2, const int* __restrict__ d2,
    const float* __restrict__ emb, const float* __restrict__ mlp_w,
    const float* __restrict__ mlp_b, float* __restrict__ logits)
{
  __shared__ __hip_bfloat16 shi[ROWS][KPAD];
  __shared__ __hip_bfloat16 slo[ROWS][KPAD];
  __shared__ int toks[ROWS];
  __shared__ float kacc2[2][4][16][KN];   // [qtile][dpair][qcol][kernel]

  const int b = blockIdx.x;
  const int pair = blockIdx.y;
  const int tid = threadIdx.x;
  const int* __restrict__ qp = pair ? q2 : q1;
  const int* __restrict__ dp = pair ? d2 : d1;

  // ---- token ids: rows 0..29 query, 30..31 pad, 32..159 doc ----
  if (tid < ROWS) {
    int t = -1;
    if (tid < LQ) t = qp[b * LQ + tid];
    else if (tid >= 32) t = dp[b * LD + (tid - 32)];
    toks[tid] = t;
  }
  __syncthreads();

  // ---- gather + L2-normalize + hi/lo bf16 split into LDS ----
  {
    const int lg = tid & 15;
    const int g = tid >> 4;            // 32 groups, one row each per iter
    #pragma unroll
    for (int it = 0; it < 5; ++it) {
      const int row = it * 32 + g;
      const int tok = toks[row];
      float4 v4 = make_float4(0.f, 0.f, 0.f, 0.f);
      if (tok >= 0) {
        if (lg < 12) {
          v4 = *(const float4*)(emb + (long)tok * EMB + 4 * lg);
        } else if (lg == 12) {          // elems 48,49 only (avoid OOB past row)
          float2 t2 = *(const float2*)(emb + (long)tok * EMB + 48);
          v4.x = t2.x; v4.y = t2.y;
        }
      }
      float ss = v4.x*v4.x + v4.y*v4.y + v4.z*v4.z + v4.w*v4.w;
      ss = grp16_sum(ss);
      const float scale = 1.0f / fmaxf(sqrtf(ss), 1e-12f);
      ushort4 hs, ls;
      const float e0 = v4.x * scale, e1 = v4.y * scale,
                  e2 = v4.z * scale, e3 = v4.w * scale;
      __hip_bfloat16 h;
      h = __float2bfloat16(e0); hs.x = __hip_bfloat16_raw(h).x;
      ls.x = __hip_bfloat16_raw(__float2bfloat16(e0 - __bfloat162float(h))).x;
      h = __float2bfloat16(e1); hs.y = __hip_bfloat16_raw(h).x;
      ls.y = __hip_bfloat16_raw(__float2bfloat16(e1 - __bfloat162float(h))).x;
      h = __float2bfloat16(e2); hs.z = __hip_bfloat16_raw(h).x;
      ls.z = __hip_bfloat16_raw(__float2bfloat16(e2 - __bfloat162float(h))).x;
      h = __float2bfloat16(e3); hs.w = __hip_bfloat16_raw(h).x;
      ls.w = __hip_bfloat16_raw(__float2bfloat16(e3 - __bfloat162float(h))).x;
      *(ushort4*)&shi[row][4 * lg] = hs;
      *(ushort4*)&slo[row][4 * lg] = ls;
    }
  }
  __syncthreads();

  // ---- phase 2: wave w = (qtile, dpair); 2 doc-tiles per wave ----
  const int lane = tid & 63;
  const int w = tid >> 6;             // 0..7
  const int qtile = w >> 2;           // 0..1
  const int dpair = w & 3;            // 0..3  -> dtiles {dpair, dpair+4}
  const int col = lane & 15;          // C col = query within tile
  const int kgrp = lane >> 4;         // 0..3
  const int klane = kgrp * 8;

  const int qrow = qtile * 16 + col;
  const short8 Bh0 = *(const short8*)&shi[qrow][klane];
  const short8 Bh1 = *(const short8*)&shi[qrow][32 + klane];
  const short8 Bl0 = *(const short8*)&slo[qrow][klane];
  const short8 Bl1 = *(const short8*)&slo[qrow][32 + klane];
  const int qtok = toks[qrow];

  f32x2 racc[20];                     // packed accumulators for the 20 RBF kernels
  #pragma unroll
  for (int k = 0; k < 20; ++k) racc[k] = (f32x2){0.0f, 0.0f};
  float cnt = 0.0f;
  const f32x2 em1 = {EM1, EM1};

  #pragma unroll 1
  for (int s = 0; s < 2; ++s) {
    const int dtile = dpair + s * 4;
    const int arow = 32 + dtile * 16 + col;      // A row = doc
    const short8 Ah0 = *(const short8*)&shi[arow][klane];
    const short8 Ah1 = *(const short8*)&shi[arow][32 + klane];
    const short8 Al0 = *(const short8*)&slo[arow][klane];
    const short8 Al1 = *(const short8*)&slo[arow][32 + klane];

    f32x4 acc = {0.0f, 0.0f, 0.0f, 0.0f};
    acc = __builtin_amdgcn_mfma_f32_16x16x32_bf16(Ah0, Bh0, acc, 0, 0, 0);
    acc = __builtin_amdgcn_mfma_f32_16x16x32_bf16(Ah1, Bh1, acc, 0, 0, 0);
    acc = __builtin_amdgcn_mfma_f32_16x16x32_bf16(Al0, Bh0, acc, 0, 0, 0);
    acc = __builtin_amdgcn_mfma_f32_16x16x32_bf16(Al1, Bh1, acc, 0, 0, 0);
    acc = __builtin_amdgcn_mfma_f32_16x16x32_bf16(Ah0, Bl0, acc, 0, 0, 0);
    acc = __builtin_amdgcn_mfma_f32_16x16x32_bf16(Ah1, Bl1, acc, 0, 0, 0);

    const int dbase = 32 + dtile * 16 + kgrp * 4; // C row = doc
    cnt += (toks[dbase + 0] == qtok) ? 1.0f : 0.0f;
    cnt += (toks[dbase + 1] == qtok) ? 1.0f : 0.0f;
    cnt += (toks[dbase + 2] == qtok) ? 1.0f : 0.0f;
    cnt += (toks[dbase + 3] == qtok) ? 1.0f : 0.0f;

    // per-point exp2 setup (native pipe: exp2; negate folds to input modifier)
    const float x0 = acc[0], x1 = acc[1], x2 = acc[2], x3 = acc[3];
    const float m0 = K10 * x0, m1 = K10 * x1, m2 = K10 * x2, m3 = K10 * x3;
    const float E0 = EXP2(m0), E1 = EXP2(m1), E2 = EXP2(m2), E3 = EXP2(m3);
    const float F0 = EXP2(-m0), F1 = EXP2(-m1), F2 = EXP2(-m2), F3 = EXP2(-m3);
    const float t0 = x0 - 0.05f, t1 = x1 - 0.05f, t2 = x2 - 0.05f, t3 = x3 - 0.05f;
    const float v0 = EXP2((-C50 * t0) * t0);
    const float v1 = EXP2((-C50 * t1) * t1);
    const float v2 = EXP2((-C50 * t2) * t2);
    const float v3 = EXP2((-C50 * t3) * t3);

    // pack points into pairs: chain ops become v_pk_mul/v_pk_add (2 pts/instr)
    const f32x2 vA = {v0, v1}, vB = {v2, v3};
    const f32x2 EA = {E0, E1}, EB = {E2, E3};
    const f32x2 FA = {F0, F1}, FB = {F2, F3};

    racc[10] += vA;
    racc[10] += vB;
    f32x2 vuA = vA, ruA = EA * em1, vuB = vB, ruB = EB * em1;
    #pragma unroll
    for (int k = 11; k <= 19; ++k) {
      vuA *= ruA; vuB *= ruB;
      racc[k] += vuA; racc[k] += vuB;
      ruA *= em1; ruB *= em1;
    }
    f32x2 vdA = vA, rdA = FA, vdB = vB, rdB = FB;
    #pragma unroll
    for (int k = 9; k >= 0; --k) {
      vdA *= rdA; vdB *= rdB;
      racc[k] += vdA; racc[k] += vdB;
      rdA *= em1; rdB *= em1;
    }
  }

  // horizontal + cross-kgrp reduction (docs) within the wave
  float out_r[KN];
  #pragma unroll
  for (int k = 0; k < 20; ++k) out_r[k] = racc[k].x + racc[k].y;
  out_r[20] = cnt;
  #pragma unroll
  for (int k = 0; k < KN; ++k) {
    out_r[k] += __shfl_xor(out_r[k], 16);
    out_r[k] += __shfl_xor(out_r[k], 32);
  }

  if (lane < 16) {
    #pragma unroll
    for (int k = 0; k < KN; ++k) kacc2[qtile][dpair][lane][k] = out_r[k];
  }
  __syncthreads();

  // ---- final: wave 0 combines 4 doc-slices, applies log1p + MLP ----
  if (tid < 64) {
    float s = 0.0f;
    if (tid < 32) {
      const int qt = tid >> 4, q = tid & 15;
      if (qt * 16 + q < LQ) {
        #pragma unroll
        for (int k = 0; k < KN; ++k) {
          const float S = kacc2[qt][0][q][k] + kacc2[qt][1][q][k] +
                          kacc2[qt][2][q][k] + kacc2[qt][3][q][k];
          s = fmaf(mlp_w[k], __logf(1.0f + S), s);
        }
      }
    }
    s += __shfl_xor(s, 1);
    s += __shfl_xor(s, 2);
    s += __shfl_xor(s, 4);
    s += __shfl_xor(s, 8);
    s += __shfl_xor(s, 16);
    s += __shfl_xor(s, 32);
    if (tid == 0) logits[pair * BATCH + b] = s + mlp_b[0];
  }
}

__global__ void knrm_combine_kernel(const float* __restrict__ logits,
                                    float* __restrict__ out) {
  int i = blockIdx.x * 256 + threadIdx.x;
  if (i < BATCH) {
    float z = logits[i] - logits[BATCH + i];
    out[i] = 1.0f / (1.0f + __expf(-z));
  }
}

extern "C" void kernel_launch(void* const* d_in, const int* in_sizes, int n_in,
                              void* d_out, int out_size, void* d_ws, size_t ws_size,
                              hipStream_t stream) {
  const int* q1 = (const int*)d_in[0];
  const int* d1 = (const int*)d_in[1];
  const int* q2 = (const int*)d_in[2];
  const int* d2 = (const int*)d_in[3];
  const float* emb = (const float*)d_in[4];
  const float* mlp_w = (const float*)d_in[5];
  const float* mlp_b = (const float*)d_in[6];
  float* out = (float*)d_out;
  float* logits = (float*)d_ws;   // 2*BATCH floats of scratch

  dim3 grid(BATCH, 2);
  knrm_pair_kernel<<<grid, THREADS, 0, stream>>>(q1, d1, q2, d2, emb, mlp_w, mlp_b, logits);
  knrm_combine_kernel<<<(BATCH + 255) / 256, 256, 0, stream>>>(logits, out);
}

// Round 6
// 139.176 us; speedup vs baseline: 1.4829x; 1.3429x over previous
//
#include <hip/hip_runtime.h>
#include <hip/hip_bf16.h>
#include <hip/hip_fp16.h>

#define BATCH 4096
#define LQ 30
#define LD 128
#define EMB 50
#define KPAD 72        // bf16 elems per row; stride 144B (bank-spread on frag reads)
#define ROWS 160       // rows 0..31 = queries (30 real), 32..159 = docs
#define KN 21
#define THREADS 512
#define K10 14.426950408889634f      // 10/ln2
#define C50 72.134752044448169f      // 50/ln2
#define KW  144.26950408889634f      // 100/ln2

typedef __attribute__((ext_vector_type(8))) short short8;
typedef __attribute__((ext_vector_type(4))) float f32x4;

#define EXP2(x) __builtin_amdgcn_exp2f(x)

// G_j = exp(-j^2/2), j = k-10, k = 0..19 (applied once after pooling)
__device__ __constant__ float Gv[20] = {
  1.928749847963918e-22f, 2.576757109154981e-18f, 1.266416554909418e-14f,
  2.269996488124243e-11f, 1.522997974471263e-08f, 3.726653172078671e-06f,
  3.354626279025119e-04f, 1.110899653824231e-02f, 1.353352832366127e-01f,
  6.065306597126334e-01f, 1.0f,
  6.065306597126334e-01f, 1.353352832366127e-01f, 1.110899653824231e-02f,
  3.354626279025119e-04f, 3.726653172078671e-06f, 1.522997974471263e-08f,
  2.269996488124243e-11f, 1.266416554909418e-14f, 2.576757109154981e-18f
};

__device__ __forceinline__ float grp16_sum(float v) {
  v += __shfl_xor(v, 8);
  v += __shfl_xor(v, 4);
  v += __shfl_xor(v, 2);
  v += __shfl_xor(v, 1);
  return v;
}

__global__ __launch_bounds__(THREADS, 4) void knrm_pair_kernel(
    const int* __restrict__ q1, const int* __restrict__ d1,
    const int* __restrict__ q2, const int* __restrict__ d2,
    const float* __restrict__ emb, const float* __restrict__ mlp_w,
    const float* __restrict__ mlp_b, float* __restrict__ logits)
{
  __shared__ __hip_bfloat16 shi[ROWS][KPAD];
  __shared__ __hip_bfloat16 slo[ROWS][KPAD];
  __shared__ int toks[ROWS];
  __shared__ __half kacc2[2][4][16][KN];   // [qtile][dpair][qcol][kernel]

  const int b = blockIdx.x;
  const int pair = blockIdx.y;
  const int tid = threadIdx.x;
  const int* __restrict__ qp = pair ? q2 : q1;
  const int* __restrict__ dp = pair ? d2 : d1;

  // ---- token ids: rows 0..29 query, 30..31 pad, 32..159 doc ----
  if (tid < ROWS) {
    int t = -1;
    if (tid < LQ) t = qp[b * LQ + tid];
    else if (tid >= 32) t = dp[b * LD + (tid - 32)];
    toks[tid] = t;
  }
  __syncthreads();

  // ---- gather + L2-normalize + hi/lo bf16 split into LDS ----
  {
    const int lg = tid & 15;
    const int g = tid >> 4;            // 32 groups, one row each per iter
    #pragma unroll
    for (int it = 0; it < 5; ++it) {
      const int row = it * 32 + g;
      const int tok = toks[row];
      float4 v4 = make_float4(0.f, 0.f, 0.f, 0.f);
      if (tok >= 0) {
        if (lg < 12) {
          v4 = *(const float4*)(emb + (long)tok * EMB + 4 * lg);
        } else if (lg == 12) {          // elems 48,49 only (avoid OOB past row)
          float2 t2 = *(const float2*)(emb + (long)tok * EMB + 48);
          v4.x = t2.x; v4.y = t2.y;
        }
      }
      float ss = v4.x*v4.x + v4.y*v4.y + v4.z*v4.z + v4.w*v4.w;
      ss = grp16_sum(ss);
      const float scale = 1.0f / fmaxf(sqrtf(ss), 1e-12f);
      ushort4 hs, ls;
      const float e0 = v4.x * scale, e1 = v4.y * scale,
                  e2 = v4.z * scale, e3 = v4.w * scale;
      __hip_bfloat16 h;
      h = __float2bfloat16(e0); hs.x = __hip_bfloat16_raw(h).x;
      ls.x = __hip_bfloat16_raw(__float2bfloat16(e0 - __bfloat162float(h))).x;
      h = __float2bfloat16(e1); hs.y = __hip_bfloat16_raw(h).x;
      ls.y = __hip_bfloat16_raw(__float2bfloat16(e1 - __bfloat162float(h))).x;
      h = __float2bfloat16(e2); hs.z = __hip_bfloat16_raw(h).x;
      ls.z = __hip_bfloat16_raw(__float2bfloat16(e2 - __bfloat162float(h))).x;
      h = __float2bfloat16(e3); hs.w = __hip_bfloat16_raw(h).x;
      ls.w = __hip_bfloat16_raw(__float2bfloat16(e3 - __bfloat162float(h))).x;
      *(ushort4*)&shi[row][4 * lg] = hs;
      *(ushort4*)&slo[row][4 * lg] = ls;
    }
  }
  __syncthreads();

  // ---- phase 2: wave w = (qtile, dpair); 2 doc-tiles per wave ----
  const int lane = tid & 63;
  const int w = tid >> 6;             // 0..7
  const int qtile = w >> 2;           // 0..1
  const int dpair = w & 3;            // 0..3  -> dtiles {dpair, dpair+4}
  const int col = lane & 15;          // C col = query within tile
  const int kgrp = lane >> 4;         // 0..3
  const int klane = kgrp * 8;

  const int qrow = qtile * 16 + col;
  const short8 Bh0 = *(const short8*)&shi[qrow][klane];
  const short8 Bh1 = *(const short8*)&shi[qrow][32 + klane];
  const short8 Bl0 = *(const short8*)&slo[qrow][klane];
  const short8 Bl1 = *(const short8*)&slo[qrow][32 + klane];
  const int qtok = toks[qrow];

  float macc[20];                    // unscaled power sums  sum v*T^j, j=k-10
  #pragma unroll
  for (int k = 0; k < 20; ++k) macc[k] = 0.0f;
  float cnt = 0.0f;

  #pragma unroll 1
  for (int s = 0; s < 2; ++s) {
    const int dtile = dpair + s * 4;
    const int arow = 32 + dtile * 16 + col;      // A row = doc
    const short8 Ah0 = *(const short8*)&shi[arow][klane];
    const short8 Ah1 = *(const short8*)&shi[arow][32 + klane];
    const short8 Al0 = *(const short8*)&slo[arow][klane];
    const short8 Al1 = *(const short8*)&slo[arow][32 + klane];

    f32x4 acc = {0.0f, 0.0f, 0.0f, 0.0f};
    acc = __builtin_amdgcn_mfma_f32_16x16x32_bf16(Ah0, Bh0, acc, 0, 0, 0);
    acc = __builtin_amdgcn_mfma_f32_16x16x32_bf16(Ah1, Bh1, acc, 0, 0, 0);
    acc = __builtin_amdgcn_mfma_f32_16x16x32_bf16(Al0, Bh0, acc, 0, 0, 0);
    acc = __builtin_amdgcn_mfma_f32_16x16x32_bf16(Al1, Bh1, acc, 0, 0, 0);
    acc = __builtin_amdgcn_mfma_f32_16x16x32_bf16(Ah0, Bl0, acc, 0, 0, 0);
    acc = __builtin_amdgcn_mfma_f32_16x16x32_bf16(Ah1, Bl1, acc, 0, 0, 0);

    const int dbase = 32 + dtile * 16 + kgrp * 4; // C row = doc
    #pragma unroll
    for (int r = 0; r < 4; ++r) {
      const float x = acc[r];
      cnt += (toks[dbase + r] == qtok) ? 1.0f : 0.0f;  // exact-match kernel
      const float t  = x - 0.05f;
      const float tt = t * t;
      const float varg = -C50 * tt;
      const float v = EXP2(varg);                 // v = e^{-50 t^2}   (j=0)
      const float T = EXP2(K10 * t);              // T = e^{10 t}
      const float wd = EXP2(fmaf(-KW, t, varg));  // w = v*T^-10      (j=-10)
      const float T2 = T * T, T3 = T2 * T, T4 = T2 * T2;
      // up chain j = 0..9
      macc[10] += v;
      macc[11] = fmaf(v, T,  macc[11]);
      macc[12] = fmaf(v, T2, macc[12]);
      macc[13] = fmaf(v, T3, macc[13]);
      float p = v * T4;                           // j=4
      macc[14] += p;
      macc[15] = fmaf(p, T,  macc[15]);
      macc[16] = fmaf(p, T2, macc[16]);
      macc[17] = fmaf(p, T3, macc[17]);
      p *= T4;                                    // j=8
      macc[18] += p;
      macc[19] = fmaf(p, T,  macc[19]);
      // down chain j = -10..-1
      macc[0] += wd;
      macc[1] = fmaf(wd, T,  macc[1]);
      macc[2] = fmaf(wd, T2, macc[2]);
      macc[3] = fmaf(wd, T3, macc[3]);
      float q = wd * T4;                          // j=-6
      macc[4] += q;
      macc[5] = fmaf(q, T,  macc[5]);
      macc[6] = fmaf(q, T2, macc[6]);
      macc[7] = fmaf(q, T3, macc[7]);
      q *= T4;                                    // j=-2
      macc[8] += q;
      macc[9] = fmaf(q, T,  macc[9]);
    }
  }

  // cross-kgrp (doc) reduction within the wave, then G_j scaling
  float out_r[KN];
  #pragma unroll
  for (int k = 0; k < 20; ++k) out_r[k] = macc[k];
  out_r[20] = cnt;
  #pragma unroll
  for (int k = 0; k < KN; ++k) {
    out_r[k] += __shfl_xor(out_r[k], 16);
    out_r[k] += __shfl_xor(out_r[k], 32);
  }

  if (lane < 16) {
    #pragma unroll
    for (int k = 0; k < 20; ++k)
      kacc2[qtile][dpair][lane][k] = __float2half(out_r[k] * Gv[k]);
    kacc2[qtile][dpair][lane][20] = __float2half(out_r[20]);
  }
  __syncthreads();

  // ---- final: wave 0 combines 4 doc-slices, applies log1p + MLP ----
  if (tid < 64) {
    float s = 0.0f;
    if (tid < 32) {
      const int qt = tid >> 4, q = tid & 15;
      if (qt * 16 + q < LQ) {
        #pragma unroll
        for (int k = 0; k < KN; ++k) {
          const float S = __half2float(kacc2[qt][0][q][k]) +
                          __half2float(kacc2[qt][1][q][k]) +
                          __half2float(kacc2[qt][2][q][k]) +
                          __half2float(kacc2[qt][3][q][k]);
          s = fmaf(mlp_w[k], __logf(1.0f + S), s);
        }
      }
    }
    s += __shfl_xor(s, 1);
    s += __shfl_xor(s, 2);
    s += __shfl_xor(s, 4);
    s += __shfl_xor(s, 8);
    s += __shfl_xor(s, 16);
    s += __shfl_xor(s, 32);
    if (tid == 0) logits[pair * BATCH + b] = s + mlp_b[0];
  }
}

__global__ void knrm_combine_kernel(const float* __restrict__ logits,
                                    float* __restrict__ out) {
  int i = blockIdx.x * 256 + threadIdx.x;
  if (i < BATCH) {
    float z = logits[i] - logits[BATCH + i];
    out[i] = 1.0f / (1.0f + __expf(-z));
  }
}

extern "C" void kernel_launch(void* const* d_in, const int* in_sizes, int n_in,
                              void* d_out, int out_size, void* d_ws, size_t ws_size,
                              hipStream_t stream) {
  const int* q1 = (const int*)d_in[0];
  const int* d1 = (const int*)d_in[1];
  const int* q2 = (const int*)d_in[2];
  const int* d2 = (const int*)d_in[3];
  const float* emb = (const float*)d_in[4];
  const float* mlp_w = (const float*)d_in[5];
  const float* mlp_b = (const float*)d_in[6];
  float* out = (float*)d_out;
  float* logits = (float*)d_ws;   // 2*BATCH floats of scratch

  dim3 grid(BATCH, 2);
  knrm_pair_kernel<<<grid, THREADS, 0, stream>>>(q1, d1, q2, d2, emb, mlp_w, mlp_b, logits);
  knrm_combine_kernel<<<(BATCH + 255) / 256, 256, 0, stream>>>(logits, out);
}